// Round 1
// baseline (111.630 us; speedup 1.0000x reference)
//
#include <hip/hip_runtime.h>
#include <math.h>

#define B 8
#define N 3072
#define T_OUTN 128
#define C_INN 32
#define D_EMBN 8
#define C_OUTN 64
#define BIGF 1e10f

// ---------------------------------------------------------------------------
// K1: per-point density weight dw[b,n] = (min same-feature nonzero |dt|)^ks
//     Blocks 0..383: b = blk/48, each handles 64 points; 4 partial i-scans.
//     Block 384: computes U[3][32][64] weight contractions.
// ---------------------------------------------------------------------------
__global__ void k1_dw(const float* __restrict__ x,
                      const float* __restrict__ W_dist, const float* __restrict__ b_dist,
                      const float* __restrict__ emb,    const float* __restrict__ W_vals,
                      const float* __restrict__ b_vals, const float* __restrict__ W_lin,
                      const float* __restrict__ ks_p,
                      float* __restrict__ dw, float* __restrict__ U) {
    const int tid = threadIdx.x;
    if (blockIdx.x == B * (N / 64)) {
        // U[comp][c][o] = sum_d W_lin[o, c*8+d] * g[comp][c][d]
        for (int e = tid; e < 3 * C_INN * C_OUTN; e += 256) {
            int comp = e / (C_INN * C_OUTN);
            int rem  = e % (C_INN * C_OUTN);
            int c = rem / C_OUTN;
            int o = rem % C_OUTN;
            float s = 0.f;
            #pragma unroll
            for (int d = 0; d < D_EMBN; ++d) {
                float w = W_lin[o * (C_INN * D_EMBN) + c * D_EMBN + d];
                float g;
                if (comp == 0)      g = W_dist[d];
                else if (comp == 1) g = b_dist[d] + b_vals[d] + emb[c * D_EMBN + d];
                else                g = W_vals[d];
                s += w * g;
            }
            U[e] = s;
        }
        return;
    }
    __shared__ __align__(16) float ts[N];
    __shared__ __align__(16) float fs[N];
    __shared__ float red[256];

    const int blk   = blockIdx.x;
    const int b     = blk / (N / 64);
    const int chunk = blk % (N / 64);
    const float* xb = x + (size_t)b * N * 3;

    for (int i = tid; i < N; i += 256) {
        fs[i] = xb[i * 3 + 0];
        ts[i] = xb[i * 3 + 2];
    }
    __syncthreads();

    const int nl   = tid & 63;   // lane = point within chunk (wave-uniform i-scan)
    const int part = tid >> 6;   // wave index = which quarter of i-range
    const int n    = chunk * 64 + nl;
    const float tn = ts[n];
    const float fn = fs[n];

    float m0 = BIGF, m1 = BIGF, m2 = BIGF, m3 = BIGF;
    const int i0 = part * (N / 4);
    #pragma unroll 2
    for (int i = i0; i < i0 + N / 4; i += 4) {
        float4 t4 = *(const float4*)&ts[i];
        float4 f4 = *(const float4*)&fs[i];
        float d0 = fabsf(t4.x - tn); if (f4.x == fn && d0 != 0.f) m0 = fminf(m0, d0);
        float d1 = fabsf(t4.y - tn); if (f4.y == fn && d1 != 0.f) m1 = fminf(m1, d1);
        float d2 = fabsf(t4.z - tn); if (f4.z == fn && d2 != 0.f) m2 = fminf(m2, d2);
        float d3 = fabsf(t4.w - tn); if (f4.w == fn && d3 != 0.f) m3 = fminf(m3, d3);
    }
    red[tid] = fminf(fminf(m0, m1), fminf(m2, m3));
    __syncthreads();
    if (part == 0) {
        float m = fminf(fminf(red[nl], red[nl + 64]),
                        fminf(red[nl + 128], red[nl + 192]));
        dw[b * N + n] = powf(m, ks_p[0]);
    }
}

// ---------------------------------------------------------------------------
// K2: per-(b,c) histogram over bin k=ceil(t), then inclusive scan over k,
//     then normalized G1/G2/G3 written to ws.
// ---------------------------------------------------------------------------
__global__ void k2_hist(const float* __restrict__ x, const float* __restrict__ dw,
                        float* __restrict__ G) {
    __shared__ float hist[4][T_OUTN];
    const int tid = threadIdx.x;
    const int b = blockIdx.x / C_INN;
    const int c = blockIdx.x % C_INN;

    for (int i = tid; i < 4 * T_OUTN; i += 256) ((float*)hist)[i] = 0.f;
    __syncthreads();

    const float* xb = x + (size_t)b * N * 3;
    for (int idx = tid; idx < N; idx += 256) {
        float fv = xb[idx * 3 + 0];
        if ((int)fv != c) continue;
        float vv = xb[idx * 3 + 1];
        float tv = xb[idx * 3 + 2];
        if (fv == 0.f && vv == 0.f && tv == 0.f) continue;   // padding mask
        float w = dw[b * N + idx];
        int k = (int)ceilf(tv);                              // contributes to tau >= k
        atomicAdd(&hist[0][k], w);
        atomicAdd(&hist[1][k], 1.f);
        atomicAdd(&hist[2][k], w * tv);
        atomicAdd(&hist[3][k], w * vv);
    }
    __syncthreads();

    // inclusive scan of 128 bins per component; one wave per component,
    // each lane owns bins 2*lane, 2*lane+1
    {
        const int comp = tid >> 6;
        const int lane = tid & 63;
        float a  = hist[comp][2 * lane];
        float bb = hist[comp][2 * lane + 1];
        float s = a + bb;
        #pragma unroll
        for (int off = 1; off < 64; off <<= 1) {
            float t = __shfl_up(s, off);
            if (lane >= off) s += t;
        }
        hist[comp][2 * lane]     = s - bb;
        hist[comp][2 * lane + 1] = s;
    }
    __syncthreads();

    if (tid < T_OUTN) {
        const int tau = tid;
        float Z   = hist[0][tau];
        float cnt = hist[1][tau];
        float St  = hist[2][tau];
        float Sv  = hist[3][tau];
        float inv = 1.f / ((Z + 1e-10f) * (cnt + 1e-10f));
        float g1 = (St - (float)tau * Z) * inv * (1.f / 127.f);
        float g2 = Z * inv;
        float g3 = Sv * inv;
        float* Gb = G + (size_t)(b * C_INN + c) * 3 * T_OUTN;
        Gb[0 * T_OUTN + tau] = g1;
        Gb[1 * T_OUTN + tau] = g2;
        Gb[2 * T_OUTN + tau] = g3;
    }
}

// ---------------------------------------------------------------------------
// K3: out[b,o,tau] = b_lin[o] + sum_c U1*G1 + U2*G2 + U3*G3
//     Block = (b, 4-tau tile); thread = (o, tau_local)
// ---------------------------------------------------------------------------
__global__ void k3_out(const float* __restrict__ U, const float* __restrict__ G,
                       const float* __restrict__ b_lin, float* __restrict__ out) {
    __shared__ __align__(16) float Us[3 * C_INN * C_OUTN];  // [comp][c][o]
    __shared__ float Gs[4 * 100];                           // [taul][c*3+comp], padded stride
    const int tid = threadIdx.x;
    const int b  = blockIdx.x >> 5;
    const int t0 = (blockIdx.x & 31) * 4;

    for (int i = tid; i < (3 * C_INN * C_OUTN) / 4; i += 256)
        ((float4*)Us)[i] = ((const float4*)U)[i];
    for (int i = tid; i < 4 * C_INN * 3; i += 256) {
        int taul = i / (C_INN * 3);
        int rem  = i % (C_INN * 3);
        int c    = rem / 3;
        int comp = rem % 3;
        Gs[taul * 100 + rem] =
            G[((size_t)(b * C_INN + c) * 3 + comp) * T_OUTN + t0 + taul];
    }
    __syncthreads();

    const int o    = tid >> 2;
    const int taul = tid & 3;
    float acc = b_lin[o];
    #pragma unroll 4
    for (int c = 0; c < C_INN; ++c) {
        float g1 = Gs[taul * 100 + c * 3 + 0];
        float g2 = Gs[taul * 100 + c * 3 + 1];
        float g3 = Gs[taul * 100 + c * 3 + 2];
        acc += Us[0 * C_INN * C_OUTN + c * C_OUTN + o] * g1
             + Us[1 * C_INN * C_OUTN + c * C_OUTN + o] * g2
             + Us[2 * C_INN * C_OUTN + c * C_OUTN + o] * g3;
    }
    out[((size_t)b * C_OUTN + o) * T_OUTN + t0 + taul] = acc;
}

// ---------------------------------------------------------------------------
extern "C" void kernel_launch(void* const* d_in, const int* in_sizes, int n_in,
                              void* d_out, int out_size, void* d_ws, size_t ws_size,
                              hipStream_t stream) {
    const float* x      = (const float*)d_in[0];
    // d_in[1] = out_positions (arange(128)) — folded into constants
    const float* W_dist = (const float*)d_in[2];
    const float* b_dist = (const float*)d_in[3];
    const float* emb    = (const float*)d_in[4];
    const float* W_vals = (const float*)d_in[5];
    const float* b_vals = (const float*)d_in[6];
    const float* W_lin  = (const float*)d_in[7];
    const float* b_lin  = (const float*)d_in[8];
    const float* ks     = (const float*)d_in[9];

    float* ws = (float*)d_ws;
    float* dw = ws;                          // B*N        = 24576 floats
    float* U  = dw + B * N;                  // 3*32*64    =  6144 floats
    float* G  = U + 3 * C_INN * C_OUTN;      // B*32*3*128 = 98304 floats
    float* out = (float*)d_out;

    k1_dw<<<B * (N / 64) + 1, 256, 0, stream>>>(x, W_dist, b_dist, emb, W_vals,
                                                b_vals, W_lin, ks, dw, U);
    k2_hist<<<B * C_INN, 256, 0, stream>>>(x, dw, G);
    k3_out<<<B * (T_OUTN / 4), 256, 0, stream>>>(U, G, b_lin, out);
}

// Round 2
// 103.163 us; speedup vs baseline: 1.0821x; 1.0821x over previous
//
#include <hip/hip_runtime.h>
#include <math.h>

#define B 8
#define N 3072
#define T_OUTN 128
#define C_INN 32
#define D_EMBN 8
#define C_OUTN 64
#define BIGF 1e10f

// ---------------------------------------------------------------------------
// K12: fused per-(b,c) pipeline.
//   Blocks 0..255: (b,c) = (blk/32, blk%32)
//     1. compact class-c points of row b into LDS (t,v)
//     2. all-pairs min same-class nonzero |dt|  (~96^2, 32x less than N^2)
//     3. dw = min^ks in-register -> histogram over bin k=ceil(t)
//     4. inclusive scan over 128 bins, write normalized G1/G2/G3
//   Block 256: U[3][32][64] weight contractions.
// ---------------------------------------------------------------------------
__global__ void k12(const float* __restrict__ x,
                    const float* __restrict__ W_dist, const float* __restrict__ b_dist,
                    const float* __restrict__ emb,    const float* __restrict__ W_vals,
                    const float* __restrict__ b_vals, const float* __restrict__ W_lin,
                    const float* __restrict__ ks_p,
                    float* __restrict__ G, float* __restrict__ U) {
    const int tid = threadIdx.x;
    if (blockIdx.x == B * C_INN) {
        // U[comp][c][o] = sum_d W_lin[o, c*8+d] * g[comp][c][d]
        for (int e = tid; e < 3 * C_INN * C_OUTN; e += 256) {
            int comp = e / (C_INN * C_OUTN);
            int rem  = e % (C_INN * C_OUTN);
            int c = rem / C_OUTN;
            int o = rem % C_OUTN;
            float s = 0.f;
            #pragma unroll
            for (int d = 0; d < D_EMBN; ++d) {
                float w = W_lin[o * (C_INN * D_EMBN) + c * D_EMBN + d];
                float g;
                if (comp == 0)      g = W_dist[d];
                else if (comp == 1) g = b_dist[d] + b_vals[d] + emb[c * D_EMBN + d];
                else                g = W_vals[d];
                s += w * g;
            }
            U[e] = s;
        }
        return;
    }

    __shared__ __align__(16) float tl[N + 4];
    __shared__ float vl[N];
    __shared__ float hist[4][T_OUTN];
    __shared__ int cnt_s;

    const int b = blockIdx.x / C_INN;
    const int c = blockIdx.x % C_INN;
    const float* xb = x + (size_t)b * N * 3;

    for (int i = tid; i < 4 * T_OUTN; i += 256) ((float*)hist)[i] = 0.f;
    if (tid == 0) cnt_s = 0;
    __syncthreads();

    // 1. compact class members (padding points included — reference's pd min
    //    does NOT mask padding; it is masked only in the histogram below)
    for (int idx = tid; idx < N; idx += 256) {
        float fv = xb[idx * 3 + 0];
        if ((int)fv == c) {
            float vv = xb[idx * 3 + 1];
            float tv = xb[idx * 3 + 2];
            int p = atomicAdd(&cnt_s, 1);
            tl[p] = tv;
            vl[p] = vv;
        }
    }
    __syncthreads();
    const int M = cnt_s;
    const int Mpad = (M + 3) & ~3;
    // pad with -BIG: |(-BIG)-tp| > BIG >= m_init, never perturbs the min
    if (tid < Mpad - M) tl[M + tid] = -BIGF;
    __syncthreads();

    // 2+3. per-point min-distance, dw, histogram
    const float ks = ks_p[0];
    for (int p = tid; p < M; p += 256) {
        const float tp = tl[p];
        const float vp = vl[p];
        float m = BIGF;
        for (int j = 0; j < Mpad; j += 4) {
            float4 t4 = *(const float4*)&tl[j];
            float d0 = fabsf(t4.x - tp); if (d0 != 0.f) m = fminf(m, d0);
            float d1 = fabsf(t4.y - tp); if (d1 != 0.f) m = fminf(m, d1);
            float d2 = fabsf(t4.z - tp); if (d2 != 0.f) m = fminf(m, d2);
            float d3 = fabsf(t4.w - tp); if (d3 != 0.f) m = fminf(m, d3);
        }
        // padding mask: f==c==0 and v==t==0
        bool pad = (c == 0) && (tp == 0.f) && (vp == 0.f);
        if (!pad) {
            float w = powf(m, ks);
            int k = (int)ceilf(tp);     // causal: contributes to all tau >= k
            atomicAdd(&hist[0][k], w);
            atomicAdd(&hist[1][k], 1.f);
            atomicAdd(&hist[2][k], w * tp);
            atomicAdd(&hist[3][k], w * vp);
        }
    }
    __syncthreads();

    // 4. inclusive scan: one wave per component, lane owns bins 2l, 2l+1
    {
        const int comp = tid >> 6;
        const int lane = tid & 63;
        float a  = hist[comp][2 * lane];
        float bb = hist[comp][2 * lane + 1];
        float s = a + bb;
        #pragma unroll
        for (int off = 1; off < 64; off <<= 1) {
            float t = __shfl_up(s, off);
            if (lane >= off) s += t;
        }
        hist[comp][2 * lane]     = s - bb;
        hist[comp][2 * lane + 1] = s;
    }
    __syncthreads();

    if (tid < T_OUTN) {
        const int tau = tid;
        float Z   = hist[0][tau];
        float cnt = hist[1][tau];
        float St  = hist[2][tau];
        float Sv  = hist[3][tau];
        float inv = 1.f / ((Z + 1e-10f) * (cnt + 1e-10f));
        float g1 = (St - (float)tau * Z) * inv * (1.f / 127.f);
        float g2 = Z * inv;
        float g3 = Sv * inv;
        float* Gb = G + (size_t)(b * C_INN + c) * 3 * T_OUTN;
        Gb[0 * T_OUTN + tau] = g1;
        Gb[1 * T_OUTN + tau] = g2;
        Gb[2 * T_OUTN + tau] = g3;
    }
}

// ---------------------------------------------------------------------------
// K3: out[b,o,tau] = b_lin[o] + sum_c U1*G1 + U2*G2 + U3*G3
// ---------------------------------------------------------------------------
__global__ void k3_out(const float* __restrict__ U, const float* __restrict__ G,
                       const float* __restrict__ b_lin, float* __restrict__ out) {
    __shared__ __align__(16) float Us[3 * C_INN * C_OUTN];  // [comp][c][o]
    __shared__ float Gs[4 * 100];                           // [taul][c*3+comp]
    const int tid = threadIdx.x;
    const int b  = blockIdx.x >> 5;
    const int t0 = (blockIdx.x & 31) * 4;

    for (int i = tid; i < (3 * C_INN * C_OUTN) / 4; i += 256)
        ((float4*)Us)[i] = ((const float4*)U)[i];
    for (int i = tid; i < 4 * C_INN * 3; i += 256) {
        int taul = i / (C_INN * 3);
        int rem  = i % (C_INN * 3);
        int c    = rem / 3;
        int comp = rem % 3;
        Gs[taul * 100 + rem] =
            G[((size_t)(b * C_INN + c) * 3 + comp) * T_OUTN + t0 + taul];
    }
    __syncthreads();

    const int o    = tid >> 2;
    const int taul = tid & 3;
    float acc = b_lin[o];
    #pragma unroll 4
    for (int c = 0; c < C_INN; ++c) {
        float g1 = Gs[taul * 100 + c * 3 + 0];
        float g2 = Gs[taul * 100 + c * 3 + 1];
        float g3 = Gs[taul * 100 + c * 3 + 2];
        acc += Us[0 * C_INN * C_OUTN + c * C_OUTN + o] * g1
             + Us[1 * C_INN * C_OUTN + c * C_OUTN + o] * g2
             + Us[2 * C_INN * C_OUTN + c * C_OUTN + o] * g3;
    }
    out[((size_t)b * C_OUTN + o) * T_OUTN + t0 + taul] = acc;
}

// ---------------------------------------------------------------------------
extern "C" void kernel_launch(void* const* d_in, const int* in_sizes, int n_in,
                              void* d_out, int out_size, void* d_ws, size_t ws_size,
                              hipStream_t stream) {
    const float* x      = (const float*)d_in[0];
    // d_in[1] = out_positions (arange(128)) — folded into constants
    const float* W_dist = (const float*)d_in[2];
    const float* b_dist = (const float*)d_in[3];
    const float* emb    = (const float*)d_in[4];
    const float* W_vals = (const float*)d_in[5];
    const float* b_vals = (const float*)d_in[6];
    const float* W_lin  = (const float*)d_in[7];
    const float* b_lin  = (const float*)d_in[8];
    const float* ks     = (const float*)d_in[9];

    float* ws = (float*)d_ws;
    float* U  = ws;                          // 3*32*64    =  6144 floats
    float* G  = U + 3 * C_INN * C_OUTN;      // B*32*3*128 = 98304 floats
    float* out = (float*)d_out;

    k12<<<B * C_INN + 1, 256, 0, stream>>>(x, W_dist, b_dist, emb, W_vals,
                                           b_vals, W_lin, ks, G, U);
    k3_out<<<B * (T_OUTN / 4), 256, 0, stream>>>(U, G, b_lin, out);
}